// Round 8
// baseline (370.535 us; speedup 1.0000x reference)
//
#include <hip/hip_runtime.h>
#include <hip/hip_bf16.h>
#include <hip/hip_fp16.h>

typedef __attribute__((ext_vector_type(8))) short short8;
typedef __attribute__((ext_vector_type(4))) float f32x4;

#define DEVI __device__ __forceinline__

DEVI unsigned short f2bf(float f){
  __hip_bfloat16 h = __float2bfloat16(f);
  unsigned short u; __builtin_memcpy(&u, &h, 2); return u;
}

// ---------------- cast fp32 -> bf16 ----------------
__global__ void cast_f32_bf16(const float* __restrict__ in, unsigned short* __restrict__ out, int n4){
  int stride = gridDim.x * blockDim.x;
  for (int i = blockIdx.x*blockDim.x + threadIdx.x; i < n4; i += stride){
    float4 f = reinterpret_cast<const float4*>(in)[i];
    ushort4 o;
    o.x = f2bf(f.x); o.y = f2bf(f.y); o.z = f2bf(f.z); o.w = f2bf(f.w);
    reinterpret_cast<ushort4*>(out)[i] = o;
  }
}

// ---------------- transpose + cast: WT[n][k] = W[k][n] ----------------
__global__ void transpose_cast_w(const float* __restrict__ W, unsigned short* __restrict__ WT, int K, int N){
  __shared__ float tile[32][33];
  int bn = blockIdx.x*32, bk = blockIdx.y*32;
  int tx = threadIdx.x & 31, ty = threadIdx.x >> 5;
  for (int r=0;r<32;r+=8)
    tile[ty+r][tx] = W[(long)(bk+ty+r)*N + bn+tx];
  __syncthreads();
  for (int r=0;r<32;r+=8)
    WT[(long)(bn+ty+r)*K + bk+tx] = (short)f2bf(tile[tx][ty+r]);
}

// ---------------- async global->LDS, 16B/lane ----------------
DEVI void stage16(const short* gsrc, short* lbase){
  __builtin_amdgcn_global_load_lds(
      (const __attribute__((address_space(1))) unsigned int*)gsrc,
      (__attribute__((address_space(3))) unsigned int*)lbase, 16, 0, 0);
}

// ---------------- 128x128 dbuf GEMM: C = scale*(A @ Bt^T) + bias ------------
// OT: 0=f32, 1=f16, 2=bf16.  BIAS: 0 none, 1 per-col, 2 per-row.
// BK=64, 256 thr = 4 waves (2M x 2N), DOUBLE-buffered LDS 64KB -> 2 blocks/CU.
// Mechanism (m97-proven): compute is ONE compiler-scheduled blob (no asm waits
// inside; compiler interleaves ds_reads under MFMAs with counted lgkmcnt);
// cross-block overlap from 2 blocks/CU; dbuf loads issued one full K-tile
// before their vmcnt(8) wait, so the wait is ~free.
// LDS (shorts): buf*16384 + op*8192 + kh*4096; 16-row subtile = 512 shorts,
// st_16x32 XOR-swizzle (verified r2-7: 0 bank conflicts).
template<int OT, int BIAS>
DEVI void gemm_db_body(const short* __restrict__ A, const short* __restrict__ Bt,
                       const float* __restrict__ bias, void* __restrict__ Cv,
                       int N, int K, long sA, long sB, long sC, float scale, int nx, int ny)
{
  extern __shared__ short lds[];
  // bijective XCD swizzle (all launches have nwg % 8 == 0)
  const int nwg = gridDim.x;
  const int cpx = nwg >> 3;
  const int wg  = (blockIdx.x & 7)*cpx + (blockIdx.x >> 3);
  const int bx  = wg % nx;
  const int tmp = wg / nx;
  const int by  = tmp % ny;
  const long bz = tmp / ny;
  const int m0 = bx * 128, n0 = by * 128;
  const short* Ab = A  + bz*sA + (long)m0 * K;
  const short* Bb = Bt + bz*sB + (long)n0 * K;

  const int t = threadIdx.x, lane = t & 63, w = t >> 6;   // 4 waves
  const int wr = w >> 1, wc = w & 1;                      // 2M x 2N

  // staging: wave w stages 16-row chunks w and w+4 of each 128-row half-block;
  // k pre-swizzled with st_16x32 involution (matches read-side XOR).
  const int rr = lane >> 2;
  const int kk = ((lane & 3) * 8) ^ ((lane & 32) ? 16 : 0);
  const long off0 = (long)(( w     )*16 + rr) * K + kk;
  const long off1 = (long)(( 4 + w )*16 + rr) * K + kk;

  // ds_read: swizzled per-lane byte offset within each 1KB (16rows x 32k) subtile
  const int la = lane & 15;
  const int lsw = (la*64 + ((lane>>4)<<4)) ^ ((la>=8)?32:0);
  const short* AP = lds + (lsw>>1) + wr*2048;          // + buf*16384 + kh*4096 + m*512
  const short* BP = lds + (lsw>>1) + 8192 + wc*2048;   // + buf*16384 + kh*4096 + n*512

  f32x4 acc[4][4] = {};
  const int NT = K >> 6;          // K-tiles of 64 (NT >= 16 for all our shapes)

#define STAGEH(BASE, BLK) do {                         \
    stage16((BASE) + off0, (BLK) + w*512);             \
    stage16((BASE) + off1, (BLK) + (4+w)*512);         \
  } while(0)
#define STAGE(BUF, KB) do {                            \
    STAGEH(Ab + (KB),      lds + (BUF)*16384 + 0);     \
    STAGEH(Ab + (KB) + 32, lds + (BUF)*16384 + 4096);  \
    STAGEH(Bb + (KB),      lds + (BUF)*16384 + 8192);  \
    STAGEH(Bb + (KB) + 32, lds + (BUF)*16384 + 12288); \
  } while(0)

  // prologue: tile0 -> buf0, tile1 -> buf1 (8 loads each)
  STAGE(0, 0);
  STAGE(1, 64);
  asm volatile("s_waitcnt vmcnt(8)" ::: "memory");   // tile0 landed; tile1 in flight
  asm volatile("s_barrier" ::: "memory");

  int cur = 0;
  for (int u = 0; u < NT; ++u){
    // ---- compute tile u from buf `cur`: plain loads + MFMAs, compiler-scheduled
    const short* ap = AP + cur*16384;
    const short* bp = BP + cur*16384;
    #pragma unroll
    for (int kh = 0; kh < 2; ++kh){
      short8 b0 = *reinterpret_cast<const short8*>(bp + kh*4096 + 0*512);
      short8 b1 = *reinterpret_cast<const short8*>(bp + kh*4096 + 1*512);
      short8 b2 = *reinterpret_cast<const short8*>(bp + kh*4096 + 2*512);
      short8 b3 = *reinterpret_cast<const short8*>(bp + kh*4096 + 3*512);
      short8 a0 = *reinterpret_cast<const short8*>(ap + kh*4096 + 0*512);
      short8 a1 = *reinterpret_cast<const short8*>(ap + kh*4096 + 1*512);
      short8 a2 = *reinterpret_cast<const short8*>(ap + kh*4096 + 2*512);
      short8 a3 = *reinterpret_cast<const short8*>(ap + kh*4096 + 3*512);
      acc[0][0] = __builtin_amdgcn_mfma_f32_16x16x32_bf16(a0, b0, acc[0][0],0,0,0);
      acc[0][1] = __builtin_amdgcn_mfma_f32_16x16x32_bf16(a0, b1, acc[0][1],0,0,0);
      acc[0][2] = __builtin_amdgcn_mfma_f32_16x16x32_bf16(a0, b2, acc[0][2],0,0,0);
      acc[0][3] = __builtin_amdgcn_mfma_f32_16x16x32_bf16(a0, b3, acc[0][3],0,0,0);
      acc[1][0] = __builtin_amdgcn_mfma_f32_16x16x32_bf16(a1, b0, acc[1][0],0,0,0);
      acc[1][1] = __builtin_amdgcn_mfma_f32_16x16x32_bf16(a1, b1, acc[1][1],0,0,0);
      acc[1][2] = __builtin_amdgcn_mfma_f32_16x16x32_bf16(a1, b2, acc[1][2],0,0,0);
      acc[1][3] = __builtin_amdgcn_mfma_f32_16x16x32_bf16(a1, b3, acc[1][3],0,0,0);
      acc[2][0] = __builtin_amdgcn_mfma_f32_16x16x32_bf16(a2, b0, acc[2][0],0,0,0);
      acc[2][1] = __builtin_amdgcn_mfma_f32_16x16x32_bf16(a2, b1, acc[2][1],0,0,0);
      acc[2][2] = __builtin_amdgcn_mfma_f32_16x16x32_bf16(a2, b2, acc[2][2],0,0,0);
      acc[2][3] = __builtin_amdgcn_mfma_f32_16x16x32_bf16(a2, b3, acc[2][3],0,0,0);
      acc[3][0] = __builtin_amdgcn_mfma_f32_16x16x32_bf16(a3, b0, acc[3][0],0,0,0);
      acc[3][1] = __builtin_amdgcn_mfma_f32_16x16x32_bf16(a3, b1, acc[3][1],0,0,0);
      acc[3][2] = __builtin_amdgcn_mfma_f32_16x16x32_bf16(a3, b2, acc[3][2],0,0,0);
      acc[3][3] = __builtin_amdgcn_mfma_f32_16x16x32_bf16(a3, b3, acc[3][3],0,0,0);
    }
    // all my reads done -> safe for others to overwrite buf `cur` after barrier
    asm volatile("s_waitcnt lgkmcnt(0)" ::: "memory");
    asm volatile("s_barrier" ::: "memory");
    // restage buf `cur` with tile u+2 (loads fly across next tile's compute)
    int u2 = u + 2; if (u2 >= NT) u2 -= NT;
    STAGE(cur, u2*64);
    // wait for tile u+1 (issued one full tile ago -> ~free); u+2's 8 stay in flight
    asm volatile("s_waitcnt vmcnt(8)" ::: "memory");
    asm volatile("s_barrier" ::: "memory");
    cur ^= 1;
  }
#undef STAGE
#undef STAGEH

  asm volatile("s_waitcnt vmcnt(0)" ::: "memory");   // drain before exit

  // ---- epilogue: direct stores (r1-verified C/D mapping) ----
  const int rowb = m0 + wr*64 + ((lane>>4)<<2);
  const int colb = n0 + wc*64 + la;
  #pragma unroll
  for (int m=0;m<4;m++){
    #pragma unroll
    for (int n=0;n<4;n++){
      const int col = colb + n*16;
      float badd = (BIAS==1) ? bias[col] : 0.0f;
      #pragma unroll
      for (int j=0;j<4;j++){
        const int row = rowb + m*16 + j;
        float v = acc[m][n][j] * scale + badd;
        if (BIAS==2) v += bias[row];
        const long idx = bz*sC + (long)row*N + col;
        if constexpr (OT==0) ((float*)Cv)[idx] = v;
        else if constexpr (OT==1) ((__half*)Cv)[idx] = __float2half(v);
        else ((unsigned short*)Cv)[idx] = f2bf(v);
      }
    }
  }
}

#define GATTR __global__ __launch_bounds__(256, 2)
GATTR void g_proj_k(const short* A, const short* Bt, const float* bias, void* Cv,
                    int N, int K, long sA, long sB, long sC, float scale, int nx, int ny)
{ gemm_db_body<2,1>(A,Bt,bias,Cv,N,K,sA,sB,sC,scale,nx,ny); }
GATTR void g_proj_v(const short* A, const short* Bt, const float* bias, void* Cv,
                    int N, int K, long sA, long sB, long sC, float scale, int nx, int ny)
{ gemm_db_body<2,2>(A,Bt,bias,Cv,N,K,sA,sB,sC,scale,nx,ny); }
GATTR void g_proj_q(const short* A, const short* Bt, const float* bias, void* Cv,
                    int N, int K, long sA, long sB, long sC, float scale, int nx, int ny)
{ gemm_db_body<2,1>(A,Bt,bias,Cv,N,K,sA,sB,sC,scale,nx,ny); }
GATTR void g_score(const short* A, const short* Bt, const float* bias, void* Cv,
                   int N, int K, long sA, long sB, long sC, float scale, int nx, int ny)
{ gemm_db_body<1,0>(A,Bt,bias,Cv,N,K,sA,sB,sC,scale,nx,ny); }
GATTR void g_pv(const short* A, const short* Bt, const float* bias, void* Cv,
                int N, int K, long sA, long sB, long sC, float scale, int nx, int ny)
{ gemm_db_body<0,0>(A,Bt,bias,Cv,N,K,sA,sB,sC,scale,nx,ny); }

// ---------------- row softmax, fp16 in -> bf16 out, in place ----------------
__global__ void softmax_rows(unsigned short* __restrict__ SP, int cols){
  const long row = blockIdx.x;
  unsigned short* rp = SP + row * cols;
  const int t = threadIdx.x, lane = t & 63, w = t >> 6;
  short8 raw = *reinterpret_cast<const short8*>(rp + t*8);
  float v[8];
  #pragma unroll
  for (int i=0;i<8;i++){
    unsigned short us = (unsigned short)raw[i];
    __half h; __builtin_memcpy(&h, &us, 2);
    v[i] = __half2float(h);
  }
  float m = v[0];
  #pragma unroll
  for (int i=1;i<8;i++) m = fmaxf(m, v[i]);
  #pragma unroll
  for (int o=32;o;o>>=1) m = fmaxf(m, __shfl_down(m, o));
  __shared__ float red[8];
  if (lane==0) red[w] = m;
  __syncthreads();
  if (t==0) red[4] = fmaxf(fmaxf(red[0],red[1]), fmaxf(red[2],red[3]));
  __syncthreads();
  const float rowmax = red[4];
  float s = 0.f;
  #pragma unroll
  for (int i=0;i<8;i++){ v[i] = __expf(v[i]-rowmax); s += v[i]; }
  #pragma unroll
  for (int o=32;o;o>>=1) s += __shfl_down(s, o);
  if (lane==0) red[w] = s;
  __syncthreads();
  if (t==0) red[5] = red[0]+red[1]+red[2]+red[3];
  __syncthreads();
  const float inv = 1.0f / red[5];
  short8 outp;
  #pragma unroll
  for (int i=0;i<8;i++) outp[i] = (short)f2bf(v[i]*inv);
  *reinterpret_cast<short8*>(rp + t*8) = outp;
}

extern "C" void kernel_launch(void* const* d_in, const int* in_sizes, int n_in,
                              void* d_out, int out_size, void* d_ws, size_t ws_size,
                              hipStream_t stream)
{
  const int B = 8, S = 2048, D = 1024;
  const int BS = B * S;                      // 16384
  const float* x1 = (const float*)d_in[0];
  const float* x2 = (const float*)d_in[1];
  const float* Wq = (const float*)d_in[2];
  const float* bq = (const float*)d_in[3];
  const float* Wk = (const float*)d_in[4];
  const float* bk = (const float*)d_in[5];
  const float* Wv = (const float*)d_in[6];
  const float* bv = (const float*)d_in[7];

  char* ws = (char*)d_ws;
  const size_t MB = 1024*1024;
  short*          x1b = (short*)(ws);             // 32MB (dead after q GEMM)
  short*          x2b = (short*)(ws + 32*MB);     // 32MB (dead after vT GEMM)
  unsigned short* Sc  = (unsigned short*)ws;      // 64MB scores/probs (reuses x1b/x2b)
  short*          q   = (short*)(ws + 64*MB);     // 32MB
  short*          k   = (short*)(ws + 96*MB);     // 32MB
  short*          vT  = (short*)(ws + 128*MB);    // 32MB [B][D][S]
  short*          WqT = (short*)(ws + 160*MB);
  short*          WkT = (short*)(ws + 162*MB);
  short*          WvT = (short*)(ws + 164*MB);    // total 166MB

  const size_t SH = 65536;  // 64KB dynamic LDS -> 2 blocks/CU

  cast_f32_bf16<<<4096,256,0,stream>>>(x2, (unsigned short*)x2b, BS*D/4);
  transpose_cast_w<<<dim3(32,32),256,0,stream>>>(Wk, (unsigned short*)WkT, D, D);
  transpose_cast_w<<<dim3(32,32),256,0,stream>>>(Wv, (unsigned short*)WvT, D, D);
  // k2 = x2 @ Wk + bk (bf16): M=BS,N=D,K=D; grid 128x8 = 1024
  g_proj_k<<<1024, 256, SH, stream>>>(x2b, WkT, bk, k, D, D, 0,0,0, 1.0f, 128, 8);
  // vT[b] = WvT @ x2[b]^T + bv(per-row): M=D,N=S,K=D; grid 8x16x8 = 1024
  g_proj_v<<<1024, 256, SH, stream>>>(WvT, x2b, bv, vT, S, D, 0, (long)S*D, (long)D*S, 1.0f, 8, 16);
  cast_f32_bf16<<<4096,256,0,stream>>>(x1, (unsigned short*)x1b, BS*D/4);
  transpose_cast_w<<<dim3(32,32),256,0,stream>>>(Wq, (unsigned short*)WqT, D, D);
  // q1 = x1 @ Wq + bq: grid 1024
  g_proj_q<<<1024, 256, SH, stream>>>(x1b, WqT, bq, q, D, D, 0,0,0, 1.0f, 128, 8);
  // scores = q k^T / 32 (fp16): M=S,N=S,K=D; grid 16x16x8 = 2048
  g_score<<<2048, 256, SH, stream>>>(q, k, nullptr, Sc, S, D,
                                     (long)S*D, (long)S*D, (long)S*S, 0.03125f, 16, 16);
  // softmax rows, in place -> bf16 probs
  softmax_rows<<<BS,256,0,stream>>>(Sc, S);
  // O = P @ V: A=P[S,S] bf16, Bt=vT[D,S], C=f32 out: M=S,N=D,K=S; grid 16x8x8 = 1024
  g_pv<<<1024, 256, SH, stream>>>((short*)Sc, vT, nullptr, d_out, D, S,
                                  (long)S*S, (long)D*S, (long)S*D, 1.0f, 16, 8);
}